// Round 8
// baseline (787.697 us; speedup 1.0000x reference)
//
#include <hip/hip_runtime.h>
#include <hip/hip_fp16.h>
#include <math.h>

#define NN 50000
#define NE 800000
#define FF 128
#define QKV_BLOCKS 782   /* ceil(50000/16/4) */

using short8 = __attribute__((ext_vector_type(8))) short;
using f32x4  = __attribute__((ext_vector_type(4))) float;
using h2     = __attribute__((ext_vector_type(2))) _Float16;

#define EXP_SCALE 5.770780163555851f   /* 4 * log2(e) */

__device__ __forceinline__ short f2bf(float x){
  union { float f; unsigned u; } c; c.f = x;
  unsigned r = c.u + 0x7FFFu + ((c.u >> 16) & 1u);
  return (short)(r >> 16);
}
__device__ __forceinline__ float bf2f(short h){
  union { unsigned u; float f; } c; c.u = ((unsigned)(unsigned short)h) << 16;
  return c.f;
}
__device__ __forceinline__ float hdot2(h2 a, h2 b){
#if __has_builtin(__builtin_amdgcn_fdot2)
  return __builtin_amdgcn_fdot2(a, b, 0.f, false);
#else
  return (float)a[0]*(float)b[0] + (float)a[1]*(float)b[1];
#endif
}
__device__ __forceinline__ float fexp2(float x){
#if __has_builtin(__builtin_amdgcn_exp2f)
  return __builtin_amdgcn_exp2f(x);
#else
  return exp2f(x);
#endif
}
__device__ __forceinline__ float clamp5(float x){
#if __has_builtin(__builtin_amdgcn_fmed3f)
  return __builtin_amdgcn_fmed3f(x, -5.f, 5.f);
#else
  return fminf(fmaxf(x, -5.f), 5.f);
#endif
}

// ---- K1: weight conversion f32 -> split bf16 (hi|lo), plus deg zero-init.
__global__ void k_cvt_w(const float* __restrict__ Wq, const float* __restrict__ Wk,
                        const float* __restrict__ Wv, const float* __restrict__ Wn,
                        const float* __restrict__ We, const float* __restrict__ Wg,
                        short* bqkv, short* bn, short* bc, int* __restrict__ deg){
  int i = blockIdx.x*256 + threadIdx.x;
  if (i < NN) deg[i] = 0;
  if (i < 16384){
    const float* W[3] = {Wq, Wk, Wv};
    #pragma unroll
    for (int j = 0; j < 3; j++){
      float x = W[j][i];
      short hi = f2bf(x);
      bqkv[j*16384 + i] = hi;
      bqkv[49152 + j*16384 + i] = f2bf(x - bf2f(hi));
    }
    float xn = Wn[i];
    short hn = f2bf(xn);
    bn[i] = hn; bn[i + 16384] = f2bf(xn - bf2f(hn));
  }
  if (i < 2048){
    float x = (i < 1024) ? We[i] : Wg[i-1024];
    short hi = f2bf(x);
    bc[i] = hi; bc[i + 2048] = f2bf(x - bf2f(hi));
  }
}

// ---- K2: fused qkv GEMM (blocks < QKV_BLOCKS) + degree histogram (rest).
__global__ void k_qkv_hist(const float* __restrict__ A, const short* __restrict__ B,
                           _Float16* __restrict__ C,
                           const int* __restrict__ dst, int* __restrict__ deg){
  if (blockIdx.x >= QKV_BLOCKS){
    int e = (blockIdx.x - QKV_BLOCKS)*256 + threadIdx.x;
    if (e < NE) atomicAdd(&deg[dst[e]], 1);
    return;
  }
  const int NC = 384;
  int w = threadIdx.x >> 6, lane = threadIdx.x & 63;
  int row0 = (blockIdx.x*4 + w)*16;
  if (row0 >= NN) return;
  int r  = lane & 15;
  int kq = lane >> 4;

  const short* Bhi = B;
  const short* Blo = B + (size_t)NC*FF;

  short8 ahi[4], alo[4];
  const float* arow = A + (size_t)(row0 + r)*FF + kq*8;
  #pragma unroll
  for (int kk = 0; kk < 4; kk++){
    float4 lo4 = *(const float4*)(arow + kk*32);
    float4 hi4 = *(const float4*)(arow + kk*32 + 4);
    float xs[8] = {lo4.x, lo4.y, lo4.z, lo4.w, hi4.x, hi4.y, hi4.z, hi4.w};
    short8 th, tl;
    #pragma unroll
    for (int j = 0; j < 8; j++){
      short hh = f2bf(xs[j]);
      th[j] = hh;
      tl[j] = f2bf(xs[j] - bf2f(hh));
    }
    ahi[kk] = th; alo[kk] = tl;
  }

  for (int ct = 0; ct < (NC >> 4); ct++){
    f32x4 acc = {0.f,0.f,0.f,0.f};
    const short* bh = Bhi + (size_t)(ct*16 + r)*FF + kq*8;
    const short* bl = Blo + (size_t)(ct*16 + r)*FF + kq*8;
    #pragma unroll
    for (int kk = 0; kk < 4; kk++){
      short8 bfh = *(const short8*)(bh + kk*32);
      short8 bfl = *(const short8*)(bl + kk*32);
      acc = __builtin_amdgcn_mfma_f32_16x16x32_bf16(ahi[kk], bfh, acc, 0, 0, 0);
      acc = __builtin_amdgcn_mfma_f32_16x16x32_bf16(ahi[kk], bfl, acc, 0, 0, 0);
      acc = __builtin_amdgcn_mfma_f32_16x16x32_bf16(alo[kk], bfh, acc, 0, 0, 0);
    }
    // D layout: col = lane&15, row = (lane>>4)*4 + reg   [measured m89/m91]
    _Float16* crow = C + (size_t)(row0 + kq*4)*NC + ct*16 + r;
    #pragma unroll
    for (int i = 0; i < 4; i++) crow[(size_t)i*NC] = (_Float16)acc[i];
  }
}

// ---- K3: 1-block exclusive scan; writes rowptr + cursor + 3 cursor copies
// (curd1..3 feed the A/B dummy k_edge replicas this round).
__global__ void k_scan(const int* __restrict__ deg, int* __restrict__ rowptr,
                       int* __restrict__ cursor, int* __restrict__ curd1,
                       int* __restrict__ curd2, int* __restrict__ curd3){
  __shared__ int sums[1024];
  const int CH = 52;                      // 1024*52 = 53248 >= 50000, 13 int4/thread
  int t = threadIdx.x;
  int base = t*CH;
  int vals[CH];
  int s = 0;
  #pragma unroll
  for (int i = 0; i < 13; i++){
    int idx = base + i*4;
    int4 v;
    if (idx + 3 < NN) v = *(const int4*)(deg + idx);
    else v = make_int4(idx < NN ? deg[idx] : 0, idx+1 < NN ? deg[idx+1] : 0,
                       idx+2 < NN ? deg[idx+2] : 0, idx+3 < NN ? deg[idx+3] : 0);
    vals[i*4+0]=v.x; vals[i*4+1]=v.y; vals[i*4+2]=v.z; vals[i*4+3]=v.w;
    s += v.x + v.y + v.z + v.w;
  }
  sums[t] = s; __syncthreads();
  for (int off = 1; off < 1024; off <<= 1){
    int val = (t >= off) ? sums[t-off] : 0;
    __syncthreads();
    sums[t] += val;
    __syncthreads();
  }
  int run = sums[t] - s;
  #pragma unroll
  for (int i = 0; i < 13; i++){
    int idx = base + i*4;
    int4 w0;
    w0.x = run; run += vals[i*4+0];
    w0.y = run; run += vals[i*4+1];
    w0.z = run; run += vals[i*4+2];
    w0.w = run; run += vals[i*4+3];
    if (idx + 3 < NN){
      *(int4*)(rowptr + idx) = w0;
      *(int4*)(cursor + idx) = w0;
      *(int4*)(curd1 + idx) = w0;
      *(int4*)(curd2 + idx) = w0;
      *(int4*)(curd3 + idx) = w0;
    } else {
      for (int q = 0; q < 4; q++){
        int id2 = idx + q;
        if (id2 < NN){
          int vv = (q==0)?w0.x:(q==1)?w0.y:(q==2)?w0.z:w0.w;
          rowptr[id2]=vv; cursor[id2]=vv; curd1[id2]=vv; curd2[id2]=vv; curd3[id2]=vv;
        }
      }
    }
  }
}

// ---- K4: fused scatter + edge GEMM.
__global__ void k_edge(const float* __restrict__ A, const short* __restrict__ B,
                       const int* __restrict__ src, const int* __restrict__ dst,
                       int* __restrict__ cursor, int* __restrict__ list,
                       float* __restrict__ ebg2){
  int w = threadIdx.x >> 6, lane = threadIdx.x & 63;
  int row0 = (blockIdx.x*4 + w)*16;
  int r  = lane & 15;
  int kq = lane >> 4;

  int pos4[4];
  if (r == 0){
    #pragma unroll
    for (int i = 0; i < 4; i++){
      int e = row0 + kq*4 + i;
      int pos = atomicAdd(&cursor[dst[e]], 1);
      list[pos] = src[e];
      pos4[i] = pos;
    }
  }

  short8 ahi[4], alo[4];
  const float* arow = A + (size_t)(row0 + r)*FF + kq*8;
  #pragma unroll
  for (int kk = 0; kk < 4; kk++){
    float4 lo4 = *(const float4*)(arow + kk*32);
    float4 hi4 = *(const float4*)(arow + kk*32 + 4);
    float xs[8] = {lo4.x, lo4.y, lo4.z, lo4.w, hi4.x, hi4.y, hi4.z, hi4.w};
    short8 th, tl;
    #pragma unroll
    for (int j = 0; j < 8; j++){
      short hh = f2bf(xs[j]);
      th[j] = hh;
      tl[j] = f2bf(xs[j] - bf2f(hh));
    }
    ahi[kk] = th; alo[kk] = tl;
  }

  f32x4 acc = {0.f,0.f,0.f,0.f};
  const short* bh = B + (size_t)r*FF + kq*8;
  const short* bl = bh + 2048;
  #pragma unroll
  for (int kk = 0; kk < 4; kk++){
    short8 bfh = *(const short8*)(bh + kk*32);
    short8 bfl = *(const short8*)(bl + kk*32);
    acc = __builtin_amdgcn_mfma_f32_16x16x32_bf16(ahi[kk], bfh, acc, 0, 0, 0);
    acc = __builtin_amdgcn_mfma_f32_16x16x32_bf16(ahi[kk], bfl, acc, 0, 0, 0);
    acc = __builtin_amdgcn_mfma_f32_16x16x32_bf16(alo[kk], bfh, acc, 0, 0, 0);
  }
  #pragma unroll
  for (int i = 0; i < 4; i++){
    int pos = __shfl(pos4[i], kq*16);      // broadcast from group leader
    float x = acc[i];
    float outv; int col;
    if (r < 8){ outv = x*EXP_SCALE; col = r*2; }
    else      { outv = 1.f/(1.f + __expf(-x)); col = (r-8)*2 + 1; }
    ebg2[(size_t)pos*16 + col] = outv;
  }
}

// ---- K5: fused aggregate (direct exp, dual streams, sequential ebg2)
__global__ void k_aggregate(const _Float16* __restrict__ qkv, const float* __restrict__ ebg2,
                            const int* __restrict__ rowptr, const int* __restrict__ cursor,
                            const int* __restrict__ list, float* __restrict__ agg){
  int w = threadIdx.x >> 6, lane = threadIdx.x & 63;
  int node = blockIdx.x*4 + w;
  if (node >= NN) return;
  int beg = rowptr[node], end = cursor[node];
  h2 kk = *(const h2*)&qkv[(size_t)node*384 + 128 + lane*2];
  int h = lane >> 3;
  float ssA=0.f, a0A=0.f, a1A=0.f;
  float ssB=0.f, a0B=0.f, a1B=0.f;
  for (int i0 = beg; i0 < end; i0 += 64){
    int nb = min(end - i0, 64);
    int sl = (i0 + lane < end) ? list[i0 + lane] : 0;
    int j = 0;
    for (; j + 1 < nb; j += 2){
      int sA = __shfl(sl, j);
      int sB = __shfl(sl, j+1);
      const _Float16* rA = qkv + (size_t)sA*384 + lane*2;
      const _Float16* rB = qkv + (size_t)sB*384 + lane*2;
      h2 qA = *(const h2*)rA;
      h2 vA = *(const h2*)(rA + 256);
      h2 qB = *(const h2*)rB;
      h2 vB = *(const h2*)(rB + 256);
      float2 ebA = *(const float2*)&ebg2[(size_t)(i0+j)*16 + h*2];
      float2 ebB = *(const float2*)&ebg2[(size_t)(i0+j+1)*16 + h*2];
      float pA = hdot2(qA, kk);
      float pB = hdot2(qB, kk);
      pA += __shfl_xor(pA, 1); pB += __shfl_xor(pB, 1);
      pA += __shfl_xor(pA, 2); pB += __shfl_xor(pB, 2);
      pA += __shfl_xor(pA, 4); pB += __shfl_xor(pB, 4);
      float tA = fexp2(fmaf(clamp5(pA), EXP_SCALE, ebA.x));
      float tB = fexp2(fmaf(clamp5(pB), EXP_SCALE, ebB.x));
      float wA = tA * ebA.y;
      float wB = tB * ebB.y;
      a0A += wA*(float)vA[0]; a1A += wA*(float)vA[1]; ssA += tA;
      a0B += wB*(float)vB[0]; a1B += wB*(float)vB[1]; ssB += tB;
    }
    if (j < nb){
      int sA = __shfl(sl, j);
      const _Float16* rA = qkv + (size_t)sA*384 + lane*2;
      h2 qA = *(const h2*)rA;
      h2 vA = *(const h2*)(rA + 256);
      float2 ebA = *(const float2*)&ebg2[(size_t)(i0+j)*16 + h*2];
      float pA = hdot2(qA, kk);
      pA += __shfl_xor(pA, 1); pA += __shfl_xor(pA, 2); pA += __shfl_xor(pA, 4);
      float tA = fexp2(fmaf(clamp5(pA), EXP_SCALE, ebA.x));
      float wA = tA * ebA.y;
      a0A += wA*(float)vA[0]; a1A += wA*(float)vA[1]; ssA += tA;
    }
  }
  float ss = ssA + ssB;
  float inv = (end > beg) ? 1.f/ss : 0.f;
  *(float2*)&agg[(size_t)node*FF + lane*2] = make_float2((a0A+a0B)*inv, (a1A+a1B)*inv);
}

// ---- K6: out GEMM (f32 out)
__global__ void k_gemm_out(const float* __restrict__ A, const short* __restrict__ B,
                           float* __restrict__ C){
  const int NC = 128;
  int w = threadIdx.x >> 6, lane = threadIdx.x & 63;
  int row0 = (blockIdx.x*4 + w)*16;
  if (row0 >= NN) return;
  int r  = lane & 15;
  int kq = lane >> 4;

  const short* Bhi = B;
  const short* Blo = B + (size_t)NC*FF;

  short8 ahi[4], alo[4];
  const float* arow = A + (size_t)(row0 + r)*FF + kq*8;
  #pragma unroll
  for (int kk = 0; kk < 4; kk++){
    float4 lo4 = *(const float4*)(arow + kk*32);
    float4 hi4 = *(const float4*)(arow + kk*32 + 4);
    float xs[8] = {lo4.x, lo4.y, lo4.z, lo4.w, hi4.x, hi4.y, hi4.z, hi4.w};
    short8 th, tl;
    #pragma unroll
    for (int j = 0; j < 8; j++){
      short hh = f2bf(xs[j]);
      th[j] = hh;
      tl[j] = f2bf(xs[j] - bf2f(hh));
    }
    ahi[kk] = th; alo[kk] = tl;
  }

  for (int ct = 0; ct < (NC >> 4); ct++){
    f32x4 acc = {0.f,0.f,0.f,0.f};
    const short* bh = Bhi + (size_t)(ct*16 + r)*FF + kq*8;
    const short* bl = Blo + (size_t)(ct*16 + r)*FF + kq*8;
    #pragma unroll
    for (int kk = 0; kk < 4; kk++){
      short8 bfh = *(const short8*)(bh + kk*32);
      short8 bfl = *(const short8*)(bl + kk*32);
      acc = __builtin_amdgcn_mfma_f32_16x16x32_bf16(ahi[kk], bfh, acc, 0, 0, 0);
      acc = __builtin_amdgcn_mfma_f32_16x16x32_bf16(ahi[kk], bfl, acc, 0, 0, 0);
      acc = __builtin_amdgcn_mfma_f32_16x16x32_bf16(alo[kk], bfh, acc, 0, 0, 0);
    }
    float* crow = C + (size_t)(row0 + kq*4)*NC + ct*16 + r;
    #pragma unroll
    for (int i = 0; i < 4; i++) crow[(size_t)i*NC] = acc[i];
  }
}

extern "C" void kernel_launch(void* const* d_in, const int* in_sizes, int n_in,
                              void* d_out, int out_size, void* d_ws, size_t ws_size,
                              hipStream_t stream) {
  const float* feat      = (const float*)d_in[0];
  const float* edge_feat = (const float*)d_in[1];
  const float* Wq        = (const float*)d_in[2];
  const float* Wk        = (const float*)d_in[3];
  const float* Wv        = (const float*)d_in[4];
  const float* Wnode     = (const float*)d_in[5];
  const float* Wedge     = (const float*)d_in[6];
  const float* Wgate     = (const float*)d_in[7];
  const int*   src       = (const int*)d_in[8];
  const int*   dst       = (const int*)d_in[9];
  float* out = (float*)d_out;

  char* p = (char*)d_ws;
  auto alloc = [&](size_t bytes)->char*{
    char* r = p; p += (bytes + 255) & ~(size_t)255; return r;
  };
  _Float16* qkv = (_Float16*)alloc((size_t)NN*384*2);
  float* ebg2   = (float*)alloc((size_t)NE*16*4);
  float* agg    = (float*)alloc((size_t)NN*FF*4);
  int*   deg    = (int*)  alloc((size_t)NN*4);
  int*   rowptr = (int*)  alloc((size_t)NN*4);
  int*   cursor = (int*)  alloc((size_t)NN*4);
  int*   curd1  = (int*)  alloc((size_t)NN*4);
  int*   curd2  = (int*)  alloc((size_t)NN*4);
  int*   curd3  = (int*)  alloc((size_t)NN*4);
  int*   list   = (int*)  alloc((size_t)NE*4);
  int*   list_d = (int*)  alloc((size_t)NE*4);
  float* ebg2_d = (float*)alloc((size_t)NE*16*4);
  short* bqkv   = (short*)alloc(2*49152*2);
  short* bn     = (short*)alloc(2*16384*2);
  short* bc     = (short*)alloc(2*2048*2);

  k_cvt_w<<<196, 256, 0, stream>>>(Wq, Wk, Wv, Wnode, Wedge, Wgate, bqkv, bn, bc, deg);

  k_qkv_hist<<<QKV_BLOCKS + (NE+255)/256, 256, 0, stream>>>(feat, bqkv, qkv, dst, deg);

  k_scan<<<1, 1024, 0, stream>>>(deg, rowptr, cursor, curd1, curd2, curd3);

  // === A/B measurement: real k_edge + 3 replicas on scratch (t_edge = Δ/3) ===
  k_edge<<<NE/64, 256, 0, stream>>>(edge_feat, bc, src, dst, cursor, list, ebg2);
  k_edge<<<NE/64, 256, 0, stream>>>(edge_feat, bc, src, dst, curd1, list_d, ebg2_d);
  k_edge<<<NE/64, 256, 0, stream>>>(edge_feat, bc, src, dst, curd2, list_d, ebg2_d);
  k_edge<<<NE/64, 256, 0, stream>>>(edge_feat, bc, src, dst, curd3, list_d, ebg2_d);

  k_aggregate<<<(NN+3)/4, 256, 0, stream>>>(qkv, ebg2, rowptr, cursor, list, agg);

  k_gemm_out<<<782, 256, 0, stream>>>(agg, bn, out);
}

// Round 9
// 358.954 us; speedup vs baseline: 2.1944x; 2.1944x over previous
//
#include <hip/hip_runtime.h>
#include <hip/hip_fp16.h>
#include <math.h>

#define NN 50000
#define NE 800000
#define FF 128
#define QKV_BLOCKS 782   /* ceil(50000/16/4) */

using short8 = __attribute__((ext_vector_type(8))) short;
using f32x4  = __attribute__((ext_vector_type(4))) float;
using h2     = __attribute__((ext_vector_type(2))) _Float16;

#define EXP_SCALE 5.770780163555851f   /* 4 * log2(e) */

__device__ __forceinline__ short f2bf(float x){
  union { float f; unsigned u; } c; c.f = x;
  unsigned r = c.u + 0x7FFFu + ((c.u >> 16) & 1u);
  return (short)(r >> 16);
}
__device__ __forceinline__ float bf2f(short h){
  union { unsigned u; float f; } c; c.u = ((unsigned)(unsigned short)h) << 16;
  return c.f;
}
__device__ __forceinline__ float hdot2(h2 a, h2 b){
#if __has_builtin(__builtin_amdgcn_fdot2)
  return __builtin_amdgcn_fdot2(a, b, 0.f, false);
#else
  return (float)a[0]*(float)b[0] + (float)a[1]*(float)b[1];
#endif
}
__device__ __forceinline__ float fexp2(float x){
#if __has_builtin(__builtin_amdgcn_exp2f)
  return __builtin_amdgcn_exp2f(x);
#else
  return exp2f(x);
#endif
}
__device__ __forceinline__ float clamp5(float x){
#if __has_builtin(__builtin_amdgcn_fmed3f)
  return __builtin_amdgcn_fmed3f(x, -5.f, 5.f);
#else
  return fminf(fmaxf(x, -5.f), 5.f);
#endif
}

// ---- K1: weight conversion f32 -> split bf16 (hi|lo), plus deg zero-init.
__global__ void k_cvt_w(const float* __restrict__ Wq, const float* __restrict__ Wk,
                        const float* __restrict__ Wv, const float* __restrict__ Wn,
                        const float* __restrict__ We, const float* __restrict__ Wg,
                        short* bqkv, short* bn, short* bc, int* __restrict__ deg){
  int i = blockIdx.x*256 + threadIdx.x;
  if (i < NN) deg[i] = 0;
  if (i < 16384){
    const float* W[3] = {Wq, Wk, Wv};
    #pragma unroll
    for (int j = 0; j < 3; j++){
      float x = W[j][i];
      short hi = f2bf(x);
      bqkv[j*16384 + i] = hi;
      bqkv[49152 + j*16384 + i] = f2bf(x - bf2f(hi));
    }
    float xn = Wn[i];
    short hn = f2bf(xn);
    bn[i] = hn; bn[i + 16384] = f2bf(xn - bf2f(hn));
  }
  if (i < 2048){
    float x = (i < 1024) ? We[i] : Wg[i-1024];
    short hi = f2bf(x);
    bc[i] = hi; bc[i + 2048] = f2bf(x - bf2f(hi));
  }
}

// ---- K2: fused qkv GEMM (blocks < QKV_BLOCKS) + degree histogram (rest).
__global__ void k_qkv_hist(const float* __restrict__ A, const short* __restrict__ B,
                           _Float16* __restrict__ C,
                           const int* __restrict__ dst, int* __restrict__ deg){
  if (blockIdx.x >= QKV_BLOCKS){
    int e = (blockIdx.x - QKV_BLOCKS)*256 + threadIdx.x;
    if (e < NE) atomicAdd(&deg[dst[e]], 1);
    return;
  }
  const int NC = 384;
  int w = threadIdx.x >> 6, lane = threadIdx.x & 63;
  int row0 = (blockIdx.x*4 + w)*16;
  if (row0 >= NN) return;
  int r  = lane & 15;
  int kq = lane >> 4;

  const short* Bhi = B;
  const short* Blo = B + (size_t)NC*FF;

  short8 ahi[4], alo[4];
  const float* arow = A + (size_t)(row0 + r)*FF + kq*8;
  #pragma unroll
  for (int kk = 0; kk < 4; kk++){
    float4 lo4 = *(const float4*)(arow + kk*32);
    float4 hi4 = *(const float4*)(arow + kk*32 + 4);
    float xs[8] = {lo4.x, lo4.y, lo4.z, lo4.w, hi4.x, hi4.y, hi4.z, hi4.w};
    short8 th, tl;
    #pragma unroll
    for (int j = 0; j < 8; j++){
      short hh = f2bf(xs[j]);
      th[j] = hh;
      tl[j] = f2bf(xs[j] - bf2f(hh));
    }
    ahi[kk] = th; alo[kk] = tl;
  }

  for (int ct = 0; ct < (NC >> 4); ct++){
    f32x4 acc = {0.f,0.f,0.f,0.f};
    const short* bh = Bhi + (size_t)(ct*16 + r)*FF + kq*8;
    const short* bl = Blo + (size_t)(ct*16 + r)*FF + kq*8;
    #pragma unroll
    for (int kk = 0; kk < 4; kk++){
      short8 bfh = *(const short8*)(bh + kk*32);
      short8 bfl = *(const short8*)(bl + kk*32);
      acc = __builtin_amdgcn_mfma_f32_16x16x32_bf16(ahi[kk], bfh, acc, 0, 0, 0);
      acc = __builtin_amdgcn_mfma_f32_16x16x32_bf16(ahi[kk], bfl, acc, 0, 0, 0);
      acc = __builtin_amdgcn_mfma_f32_16x16x32_bf16(alo[kk], bfh, acc, 0, 0, 0);
    }
    // D layout: col = lane&15, row = (lane>>4)*4 + reg   [measured m89/m91]
    _Float16* crow = C + (size_t)(row0 + kq*4)*NC + ct*16 + r;
    #pragma unroll
    for (int i = 0; i < 4; i++) crow[(size_t)i*NC] = (_Float16)acc[i];
  }
}

// ---- K3: 1-block exclusive scan of deg -> rowptr, cursor (int4 vectorized)
__global__ void k_scan(const int* __restrict__ deg, int* __restrict__ rowptr,
                       int* __restrict__ cursor){
  __shared__ int sums[1024];
  const int CH = 52;                      // 1024*52 = 53248 >= 50000, 13 int4/thread
  int t = threadIdx.x;
  int base = t*CH;
  int vals[CH];
  int s = 0;
  #pragma unroll
  for (int i = 0; i < 13; i++){
    int idx = base + i*4;
    int4 v;
    if (idx + 3 < NN) v = *(const int4*)(deg + idx);
    else v = make_int4(idx < NN ? deg[idx] : 0, idx+1 < NN ? deg[idx+1] : 0,
                       idx+2 < NN ? deg[idx+2] : 0, idx+3 < NN ? deg[idx+3] : 0);
    vals[i*4+0]=v.x; vals[i*4+1]=v.y; vals[i*4+2]=v.z; vals[i*4+3]=v.w;
    s += v.x + v.y + v.z + v.w;
  }
  sums[t] = s; __syncthreads();
  for (int off = 1; off < 1024; off <<= 1){
    int val = (t >= off) ? sums[t-off] : 0;
    __syncthreads();
    sums[t] += val;
    __syncthreads();
  }
  int run = sums[t] - s;
  #pragma unroll
  for (int i = 0; i < 13; i++){
    int idx = base + i*4;
    int4 w0;
    w0.x = run; run += vals[i*4+0];
    w0.y = run; run += vals[i*4+1];
    w0.z = run; run += vals[i*4+2];
    w0.w = run; run += vals[i*4+3];
    if (idx + 3 < NN){
      *(int4*)(rowptr + idx) = w0;
      *(int4*)(cursor + idx) = w0;
    } else {
      if (idx   < NN){ rowptr[idx  ] = w0.x; cursor[idx  ] = w0.x; }
      if (idx+1 < NN){ rowptr[idx+1] = w0.y; cursor[idx+1] = w0.y; }
      if (idx+2 < NN){ rowptr[idx+2] = w0.z; cursor[idx+2] = w0.z; }
      if (idx+3 < NN){ rowptr[idx+3] = w0.w; cursor[idx+3] = w0.w; }
    }
  }
}

// ---- K4: fused scatter + edge GEMM.
// Scatter: lanes kq==0 each own one edge (16 parallel atomics/wave, coalesced
// dst/src loads); list[pos] = {src, e}. GEMM epilogue writes ebg2 in EDGE order
// (sequential, coalesced): ebg2[e][h*2] = bias*EXP_SCALE, [h*2+1] = sigmoid(gate).
__global__ void k_edge(const float* __restrict__ A, const short* __restrict__ B,
                       const int* __restrict__ src, const int* __restrict__ dst,
                       int* __restrict__ cursor, int2* __restrict__ list,
                       float* __restrict__ ebg2){
  int w = threadIdx.x >> 6, lane = threadIdx.x & 63;
  int row0 = (blockIdx.x*4 + w)*16;
  int r  = lane & 15;
  int kq = lane >> 4;

  if (kq == 0){
    int e = row0 + r;
    int d = dst[e];
    int s = src[e];
    int pos = atomicAdd(&cursor[d], 1);
    list[pos] = make_int2(s, e);
  }

  short8 ahi[4], alo[4];
  const float* arow = A + (size_t)(row0 + r)*FF + kq*8;
  #pragma unroll
  for (int kk = 0; kk < 4; kk++){
    float4 lo4 = *(const float4*)(arow + kk*32);
    float4 hi4 = *(const float4*)(arow + kk*32 + 4);
    float xs[8] = {lo4.x, lo4.y, lo4.z, lo4.w, hi4.x, hi4.y, hi4.z, hi4.w};
    short8 th, tl;
    #pragma unroll
    for (int j = 0; j < 8; j++){
      short hh = f2bf(xs[j]);
      th[j] = hh;
      tl[j] = f2bf(xs[j] - bf2f(hh));
    }
    ahi[kk] = th; alo[kk] = tl;
  }

  f32x4 acc = {0.f,0.f,0.f,0.f};
  const short* bh = B + (size_t)r*FF + kq*8;
  const short* bl = bh + 2048;
  #pragma unroll
  for (int kk = 0; kk < 4; kk++){
    short8 bfh = *(const short8*)(bh + kk*32);
    short8 bfl = *(const short8*)(bl + kk*32);
    acc = __builtin_amdgcn_mfma_f32_16x16x32_bf16(ahi[kk], bfh, acc, 0, 0, 0);
    acc = __builtin_amdgcn_mfma_f32_16x16x32_bf16(ahi[kk], bfl, acc, 0, 0, 0);
    acc = __builtin_amdgcn_mfma_f32_16x16x32_bf16(alo[kk], bfh, acc, 0, 0, 0);
  }
  #pragma unroll
  for (int i = 0; i < 4; i++){
    int e = row0 + kq*4 + i;
    float x = acc[i];
    float outv; int col;
    if (r < 8){ outv = x*EXP_SCALE; col = r*2; }
    else      { outv = 1.f/(1.f + __expf(-x)); col = (r-8)*2 + 1; }
    ebg2[(size_t)e*16 + col] = outv;
  }
}

// ---- K5: fused aggregate. list = {src, e} in CSR order (coalesced read);
// ebg2 gathered by edge id (random 64B reads of an L3-resident 51MB buffer).
__global__ void k_aggregate(const _Float16* __restrict__ qkv, const float* __restrict__ ebg2,
                            const int* __restrict__ rowptr, const int* __restrict__ cursor,
                            const int2* __restrict__ list, float* __restrict__ agg){
  int w = threadIdx.x >> 6, lane = threadIdx.x & 63;
  int node = blockIdx.x*4 + w;
  if (node >= NN) return;
  int beg = rowptr[node], end = cursor[node];
  h2 kk = *(const h2*)&qkv[(size_t)node*384 + 128 + lane*2];
  int h = lane >> 3;
  float ssA=0.f, a0A=0.f, a1A=0.f;
  float ssB=0.f, a0B=0.f, a1B=0.f;
  for (int i0 = beg; i0 < end; i0 += 64){
    int nb = min(end - i0, 64);
    int2 es = (i0 + lane < end) ? list[i0 + lane] : make_int2(0,0);
    int j = 0;
    for (; j + 1 < nb; j += 2){
      int sA = __shfl(es.x, j);
      int eA = __shfl(es.y, j);
      int sB = __shfl(es.x, j+1);
      int eB = __shfl(es.y, j+1);
      const _Float16* rA = qkv + (size_t)sA*384 + lane*2;
      const _Float16* rB = qkv + (size_t)sB*384 + lane*2;
      h2 qA = *(const h2*)rA;
      h2 vA = *(const h2*)(rA + 256);
      h2 qB = *(const h2*)rB;
      h2 vB = *(const h2*)(rB + 256);
      float2 ebA = *(const float2*)&ebg2[(size_t)eA*16 + h*2];
      float2 ebB = *(const float2*)&ebg2[(size_t)eB*16 + h*2];
      float pA = hdot2(qA, kk);
      float pB = hdot2(qB, kk);
      pA += __shfl_xor(pA, 1); pB += __shfl_xor(pB, 1);
      pA += __shfl_xor(pA, 2); pB += __shfl_xor(pB, 2);
      pA += __shfl_xor(pA, 4); pB += __shfl_xor(pB, 4);
      float tA = fexp2(fmaf(clamp5(pA), EXP_SCALE, ebA.x));
      float tB = fexp2(fmaf(clamp5(pB), EXP_SCALE, ebB.x));
      float wA = tA * ebA.y;
      float wB = tB * ebB.y;
      a0A += wA*(float)vA[0]; a1A += wA*(float)vA[1]; ssA += tA;
      a0B += wB*(float)vB[0]; a1B += wB*(float)vB[1]; ssB += tB;
    }
    if (j < nb){
      int sA = __shfl(es.x, j);
      int eA = __shfl(es.y, j);
      const _Float16* rA = qkv + (size_t)sA*384 + lane*2;
      h2 qA = *(const h2*)rA;
      h2 vA = *(const h2*)(rA + 256);
      float2 ebA = *(const float2*)&ebg2[(size_t)eA*16 + h*2];
      float pA = hdot2(qA, kk);
      pA += __shfl_xor(pA, 1); pA += __shfl_xor(pA, 2); pA += __shfl_xor(pA, 4);
      float tA = fexp2(fmaf(clamp5(pA), EXP_SCALE, ebA.x));
      float wA = tA * ebA.y;
      a0A += wA*(float)vA[0]; a1A += wA*(float)vA[1]; ssA += tA;
    }
  }
  float ss = ssA + ssB;
  float inv = (end > beg) ? 1.f/ss : 0.f;
  *(float2*)&agg[(size_t)node*FF + lane*2] = make_float2((a0A+a0B)*inv, (a1A+a1B)*inv);
}

// ---- K6: out GEMM (f32 out)
__global__ void k_gemm_out(const float* __restrict__ A, const short* __restrict__ B,
                           float* __restrict__ C){
  const int NC = 128;
  int w = threadIdx.x >> 6, lane = threadIdx.x & 63;
  int row0 = (blockIdx.x*4 + w)*16;
  if (row0 >= NN) return;
  int r  = lane & 15;
  int kq = lane >> 4;

  const short* Bhi = B;
  const short* Blo = B + (size_t)NC*FF;

  short8 ahi[4], alo[4];
  const float* arow = A + (size_t)(row0 + r)*FF + kq*8;
  #pragma unroll
  for (int kk = 0; kk < 4; kk++){
    float4 lo4 = *(const float4*)(arow + kk*32);
    float4 hi4 = *(const float4*)(arow + kk*32 + 4);
    float xs[8] = {lo4.x, lo4.y, lo4.z, lo4.w, hi4.x, hi4.y, hi4.z, hi4.w};
    short8 th, tl;
    #pragma unroll
    for (int j = 0; j < 8; j++){
      short hh = f2bf(xs[j]);
      th[j] = hh;
      tl[j] = f2bf(xs[j] - bf2f(hh));
    }
    ahi[kk] = th; alo[kk] = tl;
  }

  for (int ct = 0; ct < (NC >> 4); ct++){
    f32x4 acc = {0.f,0.f,0.f,0.f};
    const short* bh = Bhi + (size_t)(ct*16 + r)*FF + kq*8;
    const short* bl = Blo + (size_t)(ct*16 + r)*FF + kq*8;
    #pragma unroll
    for (int kk = 0; kk < 4; kk++){
      short8 bfh = *(const short8*)(bh + kk*32);
      short8 bfl = *(const short8*)(bl + kk*32);
      acc = __builtin_amdgcn_mfma_f32_16x16x32_bf16(ahi[kk], bfh, acc, 0, 0, 0);
      acc = __builtin_amdgcn_mfma_f32_16x16x32_bf16(ahi[kk], bfl, acc, 0, 0, 0);
      acc = __builtin_amdgcn_mfma_f32_16x16x32_bf16(alo[kk], bfh, acc, 0, 0, 0);
    }
    float* crow = C + (size_t)(row0 + kq*4)*NC + ct*16 + r;
    #pragma unroll
    for (int i = 0; i < 4; i++) crow[(size_t)i*NC] = acc[i];
  }
}

extern "C" void kernel_launch(void* const* d_in, const int* in_sizes, int n_in,
                              void* d_out, int out_size, void* d_ws, size_t ws_size,
                              hipStream_t stream) {
  const float* feat      = (const float*)d_in[0];
  const float* edge_feat = (const float*)d_in[1];
  const float* Wq        = (const float*)d_in[2];
  const float* Wk        = (const float*)d_in[3];
  const float* Wv        = (const float*)d_in[4];
  const float* Wnode     = (const float*)d_in[5];
  const float* Wedge     = (const float*)d_in[6];
  const float* Wgate     = (const float*)d_in[7];
  const int*   src       = (const int*)d_in[8];
  const int*   dst       = (const int*)d_in[9];
  float* out = (float*)d_out;

  char* p = (char*)d_ws;
  auto alloc = [&](size_t bytes)->char*{
    char* r = p; p += (bytes + 255) & ~(size_t)255; return r;
  };
  _Float16* qkv = (_Float16*)alloc((size_t)NN*384*2);
  float* ebg2   = (float*)alloc((size_t)NE*16*4);
  float* agg    = (float*)alloc((size_t)NN*FF*4);
  int*   deg    = (int*)  alloc((size_t)NN*4);
  int*   rowptr = (int*)  alloc((size_t)NN*4);
  int*   cursor = (int*)  alloc((size_t)NN*4);
  int2*  list   = (int2*) alloc((size_t)NE*8);
  short* bqkv   = (short*)alloc(2*49152*2);
  short* bn     = (short*)alloc(2*16384*2);
  short* bc     = (short*)alloc(2*2048*2);

  k_cvt_w<<<196, 256, 0, stream>>>(Wq, Wk, Wv, Wnode, Wedge, Wgate, bqkv, bn, bc, deg);

  k_qkv_hist<<<QKV_BLOCKS + (NE+255)/256, 256, 0, stream>>>(feat, bqkv, qkv, dst, deg);

  k_scan<<<1, 1024, 0, stream>>>(deg, rowptr, cursor);

  k_edge<<<NE/64, 256, 0, stream>>>(edge_feat, bc, src, dst, cursor, list, ebg2);

  k_aggregate<<<(NN+3)/4, 256, 0, stream>>>(qkv, ebg2, rowptr, cursor, list, agg);

  k_gemm_out<<<782, 256, 0, stream>>>(agg, bn, out);
}